// Round 8
// baseline (262.102 us; speedup 1.0000x reference)
//
#include <hip/hip_runtime.h>
#include <hip/hip_bf16.h>

// Problem constants (GPT-2 style attention block)
#define BB 8
#define SS 1024
#define NXX 1024
#define HH 16
#define DD 64
#define MM (BB * SS)

typedef __attribute__((ext_vector_type(8))) short short8;   // 8 bf16 = 4 VGPRs
typedef __attribute__((ext_vector_type(4))) float float4v;  // MFMA C/D

// ---------------------------------------------------------------------------
// Prep kernel:
//   blocks [0, 8192):        x -> bf16 (1024 elems/block)
//   blocks [8192, 11264):    w_attn^T (32x32 tiles); Q rows (n<1024) x0.125
//   blocks [11264, 12288):   w_proj^T (32x32 tiles)
//   block 12288:             bias_s = b_attn, Q part x0.125
// ---------------------------------------------------------------------------
__global__ __launch_bounds__(256) void prep_kernel(
    const float* __restrict__ x, __hip_bfloat16* __restrict__ xb,
    const float* __restrict__ w_attn, __hip_bfloat16* __restrict__ wT_attn,
    const float* __restrict__ w_proj, __hip_bfloat16* __restrict__ wT_proj,
    const float* __restrict__ b_attn, float* __restrict__ bias_s)
{
    __shared__ __hip_bfloat16 tile[32][33];
    const int blk = blockIdx.x;
    const int tid = threadIdx.x;

    if (blk < 8192) {
        int i = blk * 1024 + tid * 4;
        float4 v = *(const float4*)(x + i);
        xb[i + 0] = __float2bfloat16(v.x);
        xb[i + 1] = __float2bfloat16(v.y);
        xb[i + 2] = __float2bfloat16(v.z);
        xb[i + 3] = __float2bfloat16(v.w);
        return;
    }
    if (blk == 12288) {
#pragma unroll
        for (int j = 0; j < 12; ++j) {
            int c = j * 256 + tid;
            bias_s[c] = b_attn[c] * (c < 1024 ? 0.125f : 1.0f);
        }
        return;
    }
    const float* W;
    __hip_bfloat16* Wt;
    int K, N, idx;
    float scale = 1.0f;
    if (blk < 8192 + 3072) { idx = blk - 8192;  W = w_attn; Wt = wT_attn; K = NXX; N = 3 * NXX; }
    else                   { idx = blk - 11264; W = w_proj; Wt = wT_proj; K = NXX; N = NXX; }
    const int k0 = (idx % (K / 32)) * 32;
    const int n0 = (idx / (K / 32)) * 32;
    if (W == w_attn && n0 < 1024) scale = 0.125f;  // Q rows of wT_attn
    const int tx = tid % 32;
    const int ty = tid / 32;
#pragma unroll
    for (int p = 0; p < 4; ++p) {
        int k = ty + p * 8;
        tile[k][tx] = __float2bfloat16(W[(size_t)(k0 + k) * N + n0 + tx] * scale);
    }
    __syncthreads();
#pragma unroll
    for (int p = 0; p < 4; ++p) {
        int nn = ty + p * 8;
        Wt[(size_t)(n0 + nn) * K + k0 + tx] = tile[tx][nn];
    }
}

// ---------------------------------------------------------------------------
// QKV GEMM: qkv = xb @ wT_attn^T + bias_s, bf16 out. 128x128 tile, BK=64
// (R7->R8: halves per-block barrier count 32->16; LDS 32 KB, still
// VGPR-occupancy-capped at 3 blocks/CU so no m132-style LDS cliff).
// ---------------------------------------------------------------------------
__global__ __launch_bounds__(256) void gemm_qkv(
    const __hip_bfloat16* __restrict__ A,   // M x K row-major
    const __hip_bfloat16* __restrict__ Bt,  // N x K row-major
    const float* __restrict__ bias,
    __hip_bfloat16* __restrict__ C,
    int M, int K, int N)
{
    __shared__ __hip_bfloat16 As[128 * 64];  // 16 KB
    __shared__ __hip_bfloat16 Bs[128 * 64];  // 16 KB

    const int tid  = threadIdx.x;
    const int wave = tid >> 6;
    const int lane = tid & 63;
    const int m0 = blockIdx.x * 128;
    const int n0 = blockIdx.y * 128;
    const int wm = (wave & 1) * 64;
    const int wn = (wave >> 1) * 64;

    float4v acc[4][4];
#pragma unroll
    for (int i = 0; i < 4; ++i)
#pragma unroll
        for (int j = 0; j < 4; ++j) acc[i][j] = (float4v){0.f, 0.f, 0.f, 0.f};

    const int fr = lane & 15;
    const int fk = (lane >> 4) * 8;
    const short* AsS = (const short*)As;
    const short* BsS = (const short*)Bs;

    for (int k0 = 0; k0 < K; k0 += 64) {
        // Stage 128x64 tiles: chunk c -> row=c>>3, k8=(c&7)*8; LDS off = c*16 B.
#pragma unroll
        for (int j = 0; j < 4; ++j) {
            int c = j * 256 + tid;
            int row = c >> 3;
            int kk = (c & 7) * 8;
            const __hip_bfloat16* ga = A + (size_t)(m0 + row) * K + k0 + kk;
            const __hip_bfloat16* gb = Bt + (size_t)(n0 + row) * K + k0 + kk;
            char* la = (char*)As + j * 4096 + (wave << 10);
            char* lb = (char*)Bs + j * 4096 + (wave << 10);
            __builtin_amdgcn_global_load_lds(
                (const __attribute__((address_space(1))) void*)ga,
                (__attribute__((address_space(3))) void*)la, 16, 0, 0);
            __builtin_amdgcn_global_load_lds(
                (const __attribute__((address_space(1))) void*)gb,
                (__attribute__((address_space(3))) void*)lb, 16, 0, 0);
        }
        __syncthreads();

#pragma unroll
        for (int kc = 0; kc < 2; ++kc) {
            short8 a_frag[4], b_frag[4];
#pragma unroll
            for (int i = 0; i < 4; ++i) {
                a_frag[i] = *(const short8*)(AsS + (wm + i * 16 + fr) * 64 + kc * 32 + fk);
                b_frag[i] = *(const short8*)(BsS + (wn + i * 16 + fr) * 64 + kc * 32 + fk);
            }
#pragma unroll
            for (int i = 0; i < 4; ++i)
#pragma unroll
                for (int j = 0; j < 4; ++j)
                    acc[i][j] = __builtin_amdgcn_mfma_f32_16x16x32_bf16(
                        a_frag[i], b_frag[j], acc[i][j], 0, 0, 0);
        }
        __syncthreads();
    }

    // C/D map: col = lane&15, row = (lane>>4)*4 + reg
    const int cr = (lane >> 4) * 4;
    const int cc = lane & 15;
#pragma unroll
    for (int i = 0; i < 4; ++i) {
        int grow = m0 + wm + i * 16 + cr;
#pragma unroll
        for (int j = 0; j < 4; ++j) {
            int gcol = n0 + wn + j * 16 + cc;
            float bv = bias[gcol];
#pragma unroll
            for (int r = 0; r < 4; ++r)
                C[(size_t)(grow + r) * N + gcol] =
                    __float2bfloat16(acc[i][j][r] + bv);
        }
    }
}

// ---------------------------------------------------------------------------
// V transpose: vT[(b*H+h)*64+d][s] = qkv[(b*S+s)*3072 + 2048 + h*64 + d].
// ---------------------------------------------------------------------------
__global__ __launch_bounds__(256) void vtrans_kernel(
    const __hip_bfloat16* __restrict__ qkv, __hip_bfloat16* __restrict__ vT)
{
    __shared__ __hip_bfloat16 Ts[256 * 72];
    const int bh = blockIdx.x;
    const int b = bh >> 4, h = bh & 15;
    const int s0 = blockIdx.y * 256;
    const int tid = threadIdx.x;

    const __hip_bfloat16* g =
        qkv + (size_t)(b * SS + s0 + tid) * 3072 + 2048 + h * 64;
#pragma unroll
    for (int j = 0; j < 8; ++j)
        *(short8*)&Ts[tid * 72 + j * 8] = *(const short8*)(g + j * 8);
    __syncthreads();

    const int d  = tid >> 2;
    const int sb = (tid & 3) * 64;
    __hip_bfloat16* o = vT + (size_t)(bh * 64 + d) * SS + s0 + sb;
#pragma unroll
    for (int j = 0; j < 8; ++j) {
        short8 p;
#pragma unroll
        for (int i = 0; i < 8; ++i)
            p[i] = *(const short*)&Ts[(sb + j * 8 + i) * 72 + d];
        *(short8*)(o + j * 8) = p;
    }
}

// ---------------------------------------------------------------------------
// Proj GEMM: 64x128 tile (1024 blocks = 4/CU), BK=64, fp32 out + bias.
// ---------------------------------------------------------------------------
__global__ __launch_bounds__(256) void gemm_proj(
    const __hip_bfloat16* __restrict__ A,   // M x K row-major
    const __hip_bfloat16* __restrict__ Bt,  // N x K row-major
    const float* __restrict__ bias,
    float* __restrict__ C,
    int M, int K, int N)
{
    __shared__ __hip_bfloat16 As[64 * 64];   // 8 KB
    __shared__ __hip_bfloat16 Bs[128 * 64];  // 16 KB

    const int tid  = threadIdx.x;
    const int wave = tid >> 6;
    const int lane = tid & 63;
    const int m0 = blockIdx.x * 64;
    const int n0 = blockIdx.y * 128;
    const int wm = (wave & 1) * 32;
    const int wn = (wave >> 1) * 64;

    float4v acc[2][4];
#pragma unroll
    for (int i = 0; i < 2; ++i)
#pragma unroll
        for (int j = 0; j < 4; ++j) acc[i][j] = (float4v){0.f, 0.f, 0.f, 0.f};

    const int fr = lane & 15;
    const int fk = (lane >> 4) * 8;
    const short* AsS = (const short*)As;
    const short* BsS = (const short*)Bs;

    for (int k0 = 0; k0 < K; k0 += 64) {
#pragma unroll
        for (int j = 0; j < 2; ++j) {  // A: 512 chunks
            int c = j * 256 + tid;
            int row = c >> 3;
            int kk = (c & 7) * 8;
            const __hip_bfloat16* ga = A + (size_t)(m0 + row) * K + k0 + kk;
            char* la = (char*)As + j * 4096 + (wave << 10);
            __builtin_amdgcn_global_load_lds(
                (const __attribute__((address_space(1))) void*)ga,
                (__attribute__((address_space(3))) void*)la, 16, 0, 0);
        }
#pragma unroll
        for (int j = 0; j < 4; ++j) {  // B: 1024 chunks
            int c = j * 256 + tid;
            int row = c >> 3;
            int kk = (c & 7) * 8;
            const __hip_bfloat16* gb = Bt + (size_t)(n0 + row) * K + k0 + kk;
            char* lb = (char*)Bs + j * 4096 + (wave << 10);
            __builtin_amdgcn_global_load_lds(
                (const __attribute__((address_space(1))) void*)gb,
                (__attribute__((address_space(3))) void*)lb, 16, 0, 0);
        }
        __syncthreads();

#pragma unroll
        for (int kc = 0; kc < 2; ++kc) {
            short8 a_frag[2], b_frag[4];
#pragma unroll
            for (int i = 0; i < 2; ++i)
                a_frag[i] = *(const short8*)(AsS + (wm + i * 16 + fr) * 64 + kc * 32 + fk);
#pragma unroll
            for (int j = 0; j < 4; ++j)
                b_frag[j] = *(const short8*)(BsS + (wn + j * 16 + fr) * 64 + kc * 32 + fk);
#pragma unroll
            for (int i = 0; i < 2; ++i)
#pragma unroll
                for (int j = 0; j < 4; ++j)
                    acc[i][j] = __builtin_amdgcn_mfma_f32_16x16x32_bf16(
                        a_frag[i], b_frag[j], acc[i][j], 0, 0, 0);
        }
        __syncthreads();
    }

    const int cr = (lane >> 4) * 4;
    const int cc = lane & 15;
#pragma unroll
    for (int i = 0; i < 2; ++i) {
        int grow = m0 + wm + i * 16 + cr;
#pragma unroll
        for (int j = 0; j < 4; ++j) {
            int gcol = n0 + wn + j * 16 + cc;
            float bv = bias[gcol];
#pragma unroll
            for (int r = 0; r < 4; ++r)
                C[(size_t)(grow + r) * N + gcol] = acc[i][j][r] + bv;
        }
    }
}

// ---------------------------------------------------------------------------
// MFMA causal flash attention, no-max softmax (scores bounded; exp(-1e10)=0).
// Block: (b,h) x 128 queries, 4 waves x (2 x 16q subtiles). 64-key tiles.
// ---------------------------------------------------------------------------
#define PSTR 72

__global__ __launch_bounds__(256) void attn_mfma_kernel(
    const __hip_bfloat16* __restrict__ qkv,
    const __hip_bfloat16* __restrict__ vT,
    __hip_bfloat16* __restrict__ aout)
{
    const int bh = blockIdx.x;
    const int b = bh / HH, h = bh % HH;
    const int q0 = ((int)gridDim.y - 1 - (int)blockIdx.y) * 128;  // heavy first

    __shared__ __hip_bfloat16 Ks[64 * PSTR];     // [key][d]
    __shared__ __hip_bfloat16 Vs[64 * PSTR];     // V^T: [d][key]
    __shared__ __hip_bfloat16 Ps[4][32 * PSTR];  // per-wave P, [q_local][key]

    const int tid  = threadIdx.x;
    const int wave = tid >> 6;
    const int lane = tid & 63;
    const int quad = lane >> 4;
    const int l16  = lane & 15;

    short8 qf[2][2];
#pragma unroll
    for (int t = 0; t < 2; ++t) {
        const __hip_bfloat16* qp = qkv +
            (size_t)(b * SS + q0 + wave * 32 + t * 16 + l16) * 3072 + h * 64 + quad * 8;
        qf[t][0] = *(const short8*)qp;
        qf[t][1] = *(const short8*)(qp + 32);
    }

    float4v o_acc[2][4];
    float l_acc[2][4];
#pragma unroll
    for (int t = 0; t < 2; ++t)
#pragma unroll
        for (int nt = 0; nt < 4; ++nt) o_acc[t][nt] = (float4v){0.f, 0.f, 0.f, 0.f};
#pragma unroll
    for (int t = 0; t < 2; ++t)
#pragma unroll
        for (int r = 0; r < 4; ++r) l_acc[t][r] = 0.f;

    const int sk  = tid & 63;
    const int sdo = (tid >> 6) * 16;
    const int vd  = tid >> 2;
    const int vko = (tid & 3) * 16;
    const int qmin_w = q0 + wave * 32;
    const int nkt = q0 / 64 + 2;

    for (int kt = 0; kt < nkt; ++kt) {
        const int k0 = kt * 64;
        __syncthreads();
        {
            const __hip_bfloat16* kr =
                qkv + (size_t)(b * SS + k0 + sk) * 3072 + 1024 + h * 64 + sdo;
            *(short8*)&Ks[sk * PSTR + sdo]     = *(const short8*)kr;
            *(short8*)&Ks[sk * PSTR + sdo + 8] = *(const short8*)(kr + 8);
            const __hip_bfloat16* vr = vT + (size_t)(bh * 64 + vd) * SS + k0 + vko;
            *(short8*)&Vs[vd * PSTR + vko]     = *(const short8*)vr;
            *(short8*)&Vs[vd * PSTR + vko + 8] = *(const short8*)(vr + 8);
        }
        __syncthreads();
        if (k0 > qmin_w + 31) continue;

        const short* ks = (const short*)Ks;
        float4v sacc[2][4];
#pragma unroll
        for (int t = 0; t < 2; ++t)
#pragma unroll
            for (int nt = 0; nt < 4; ++nt) sacc[t][nt] = (float4v){0.f, 0.f, 0.f, 0.f};
#pragma unroll
        for (int kc = 0; kc < 2; ++kc)
#pragma unroll
            for (int nt = 0; nt < 4; ++nt) {
                short8 kb = *(const short8*)(ks + (nt * 16 + l16) * PSTR + kc * 32 + quad * 8);
                sacc[0][nt] = __builtin_amdgcn_mfma_f32_16x16x32_bf16(qf[0][kc], kb, sacc[0][nt], 0, 0, 0);
                sacc[1][nt] = __builtin_amdgcn_mfma_f32_16x16x32_bf16(qf[1][kc], kb, sacc[1][nt], 0, 0, 0);
            }

        const bool needmask = (k0 + 63 > qmin_w);
        __hip_bfloat16* pw = Ps[wave];
#pragma unroll
        for (int t = 0; t < 2; ++t)
#pragma unroll
            for (int nt = 0; nt < 4; ++nt) {
                int kk = k0 + nt * 16 + l16;
#pragma unroll
                for (int r = 0; r < 4; ++r) {
                    float s = sacc[t][nt][r];
                    if (needmask) {
                        int qq = qmin_w + t * 16 + quad * 4 + r;
                        if (kk > qq) s = -1e10f;
                    }
                    float p = __expf(s);
                    l_acc[t][r] += p;
                    pw[(t * 16 + quad * 4 + r) * PSTR + nt * 16 + l16] =
                        __float2bfloat16(p);
                }
            }

        const short* ps = (const short*)pw;
        const short* vs = (const short*)Vs;
#pragma unroll
        for (int kc = 0; kc < 2; ++kc) {
            short8 pa0 = *(const short8*)(ps + (0 * 16 + l16) * PSTR + kc * 32 + quad * 8);
            short8 pa1 = *(const short8*)(ps + (1 * 16 + l16) * PSTR + kc * 32 + quad * 8);
#pragma unroll
            for (int nt = 0; nt < 4; ++nt) {
                short8 vb = *(const short8*)(vs + (nt * 16 + l16) * PSTR + kc * 32 + quad * 8);
                o_acc[0][nt] = __builtin_amdgcn_mfma_f32_16x16x32_bf16(pa0, vb, o_acc[0][nt], 0, 0, 0);
                o_acc[1][nt] = __builtin_amdgcn_mfma_f32_16x16x32_bf16(pa1, vb, o_acc[1][nt], 0, 0, 0);
            }
        }
    }

#pragma unroll
    for (int t = 0; t < 2; ++t)
#pragma unroll
        for (int r = 0; r < 4; ++r) {
            float l = l_acc[t][r];
            l += __shfl_xor(l, 1);
            l += __shfl_xor(l, 2);
            l += __shfl_xor(l, 4);
            l += __shfl_xor(l, 8);
            float inv = 1.f / l;
            int row = q0 + wave * 32 + t * 16 + quad * 4 + r;
            __hip_bfloat16* op = aout + (size_t)(b * SS + row) * NXX + h * 64 + l16;
#pragma unroll
            for (int nt = 0; nt < 4; ++nt)
                op[nt * 16] = __float2bfloat16(o_acc[t][nt][r] * inv);
        }
}

// ---------------------------------------------------------------------------
// Workspace (~88 MB):
//   [0, 48M)    qkv bf16 (Q scaled 1/8, K, V rows)
//   [48, 64M)   vT bf16 [b,h,d,s]
//   [64, 80M)   xb bf16 -- reused as amid after QKV GEMM
//   [80, 86M)   wT_attn bf16 (Q rows pre-scaled)
//   [86, 88M)   wT_proj bf16
//   [88M, +12K) bias_s fp32
// ---------------------------------------------------------------------------
extern "C" void kernel_launch(void* const* d_in, const int* in_sizes, int n_in,
                              void* d_out, int out_size, void* d_ws, size_t ws_size,
                              hipStream_t stream)
{
    const float* x      = (const float*)d_in[0];
    const float* w_attn = (const float*)d_in[1];
    const float* b_attn = (const float*)d_in[2];
    const float* w_proj = (const float*)d_in[3];
    const float* b_proj = (const float*)d_in[4];
    float* out = (float*)d_out;

    char* ws = (char*)d_ws;
    __hip_bfloat16* qkv     = (__hip_bfloat16*)ws;
    __hip_bfloat16* vT      = (__hip_bfloat16*)(ws + (size_t)48 * 1024 * 1024);
    __hip_bfloat16* xb      = (__hip_bfloat16*)(ws + (size_t)64 * 1024 * 1024);
    __hip_bfloat16* amid    = xb;
    __hip_bfloat16* wT_attn = (__hip_bfloat16*)(ws + (size_t)80 * 1024 * 1024);
    __hip_bfloat16* wT_proj = (__hip_bfloat16*)(ws + (size_t)86 * 1024 * 1024);
    float*          bias_s  = (float*)(ws + (size_t)88 * 1024 * 1024);

    dim3 blk(256);

    prep_kernel<<<dim3(12289), blk, 0, stream>>>(
        x, xb, w_attn, wT_attn, w_proj, wT_proj, b_attn, bias_s);

    gemm_qkv<<<dim3(MM / 128, 24), blk, 0, stream>>>(
        xb, wT_attn, bias_s, qkv, MM, NXX, 3 * NXX);

    vtrans_kernel<<<dim3(BB * HH, SS / 256), blk, 0, stream>>>(qkv, vT);

    attn_mfma_kernel<<<dim3(BB * HH, SS / 128), blk, 0, stream>>>(qkv, vT, amid);

    gemm_proj<<<dim3(MM / 64, NXX / 128), blk, 0, stream>>>(
        amid, wT_proj, b_proj, out, MM, NXX, NXX);
}

// Round 9
// 249.185 us; speedup vs baseline: 1.0518x; 1.0518x over previous
//
#include <hip/hip_runtime.h>
#include <hip/hip_bf16.h>

// Problem constants (GPT-2 style attention block)
#define BB 8
#define SS 1024
#define NXX 1024
#define HH 16
#define DD 64
#define MM (BB * SS)

typedef __attribute__((ext_vector_type(8))) short short8;   // 8 bf16 = 4 VGPRs
typedef __attribute__((ext_vector_type(4))) float float4v;  // MFMA C/D

// ---------------------------------------------------------------------------
// Prep kernel:
//   blocks [0, 8192):        x -> bf16 (1024 elems/block)
//   blocks [8192, 11264):    w_attn^T (32x32 tiles); Q rows (n<1024) x0.125
//   blocks [11264, 12288):   w_proj^T (32x32 tiles)
//   block 12288:             bias_s = b_attn, Q part x0.125
// ---------------------------------------------------------------------------
__global__ __launch_bounds__(256) void prep_kernel(
    const float* __restrict__ x, __hip_bfloat16* __restrict__ xb,
    const float* __restrict__ w_attn, __hip_bfloat16* __restrict__ wT_attn,
    const float* __restrict__ w_proj, __hip_bfloat16* __restrict__ wT_proj,
    const float* __restrict__ b_attn, float* __restrict__ bias_s)
{
    __shared__ __hip_bfloat16 tile[32][33];
    const int blk = blockIdx.x;
    const int tid = threadIdx.x;

    if (blk < 8192) {
        int i = blk * 1024 + tid * 4;
        float4 v = *(const float4*)(x + i);
        xb[i + 0] = __float2bfloat16(v.x);
        xb[i + 1] = __float2bfloat16(v.y);
        xb[i + 2] = __float2bfloat16(v.z);
        xb[i + 3] = __float2bfloat16(v.w);
        return;
    }
    if (blk == 12288) {
#pragma unroll
        for (int j = 0; j < 12; ++j) {
            int c = j * 256 + tid;
            bias_s[c] = b_attn[c] * (c < 1024 ? 0.125f : 1.0f);
        }
        return;
    }
    const float* W;
    __hip_bfloat16* Wt;
    int K, N, idx;
    float scale = 1.0f;
    if (blk < 8192 + 3072) { idx = blk - 8192;  W = w_attn; Wt = wT_attn; K = NXX; N = 3 * NXX; }
    else                   { idx = blk - 11264; W = w_proj; Wt = wT_proj; K = NXX; N = NXX; }
    const int k0 = (idx % (K / 32)) * 32;
    const int n0 = (idx / (K / 32)) * 32;
    if (W == w_attn && n0 < 1024) scale = 0.125f;  // Q rows of wT_attn
    const int tx = tid % 32;
    const int ty = tid / 32;
#pragma unroll
    for (int p = 0; p < 4; ++p) {
        int k = ty + p * 8;
        tile[k][tx] = __float2bfloat16(W[(size_t)(k0 + k) * N + n0 + tx] * scale);
    }
    __syncthreads();
#pragma unroll
    for (int p = 0; p < 4; ++p) {
        int nn = ty + p * 8;
        Wt[(size_t)(n0 + nn) * K + k0 + tx] = tile[tx][nn];
    }
}

// ---------------------------------------------------------------------------
// QKV GEMM: qkv = xb @ wT_attn^T + bias_s, bf16 out. 128x128 tile, BK=32
// (reverted from BK=64: R8 showed 3x bank conflicts + occupancy loss).
// NEW: XOR k-chunk swizzle. LDS chunk (row,kpos) holds global k-chunk
// kpos ^ ((row>>1)&3). Staging stays lane-order (writes conflict-free);
// fragment reads now land 2 lanes/bank-group (2-way = free, m136) instead
// of the 8-way aliasing of the plain 64 B-row-stride layout.
// ---------------------------------------------------------------------------
__global__ __launch_bounds__(256) void gemm_qkv(
    const __hip_bfloat16* __restrict__ A,   // M x K row-major
    const __hip_bfloat16* __restrict__ Bt,  // N x K row-major
    const float* __restrict__ bias,
    __hip_bfloat16* __restrict__ C,
    int M, int K, int N)
{
    __shared__ __hip_bfloat16 As[128 * 32];
    __shared__ __hip_bfloat16 Bs[128 * 32];

    const int tid  = threadIdx.x;
    const int wave = tid >> 6;
    const int lane = tid & 63;
    const int m0 = blockIdx.x * 128;
    const int n0 = blockIdx.y * 128;
    const int wm = (wave & 1) * 64;
    const int wn = (wave >> 1) * 64;

    float4v acc[4][4];
#pragma unroll
    for (int i = 0; i < 4; ++i)
#pragma unroll
        for (int j = 0; j < 4; ++j) acc[i][j] = (float4v){0.f, 0.f, 0.f, 0.f};

    const int fr = lane & 15;
    const int quad = lane >> 4;
    const short* AsS = (const short*)As;
    const short* BsS = (const short*)Bs;

    for (int k0 = 0; k0 < K; k0 += 32) {
#pragma unroll
        for (int j = 0; j < 2; ++j) {
            int c = j * 256 + tid;
            int row = c >> 2;
            // swizzled global k-chunk for this LDS slot: (c&3) ^ ((row>>1)&3)
            int kk = (((c & 3) ^ ((c >> 3) & 3)) * 8);
            const __hip_bfloat16* ga = A + (size_t)(m0 + row) * K + k0 + kk;
            const __hip_bfloat16* gb = Bt + (size_t)(n0 + row) * K + k0 + kk;
            char* la = (char*)As + j * 4096 + (wave << 10);
            char* lb = (char*)Bs + j * 4096 + (wave << 10);
            __builtin_amdgcn_global_load_lds(
                (const __attribute__((address_space(1))) void*)ga,
                (__attribute__((address_space(3))) void*)la, 16, 0, 0);
            __builtin_amdgcn_global_load_lds(
                (const __attribute__((address_space(1))) void*)gb,
                (__attribute__((address_space(3))) void*)lb, 16, 0, 0);
        }
        __syncthreads();

        short8 a_frag[4], b_frag[4];
#pragma unroll
        for (int i = 0; i < 4; ++i) {
            int ra = wm + i * 16 + fr;
            int rb = wn + i * 16 + fr;
            a_frag[i] = *(const short8*)(AsS + ra * 32 + ((quad ^ ((ra >> 1) & 3)) * 8));
            b_frag[i] = *(const short8*)(BsS + rb * 32 + ((quad ^ ((rb >> 1) & 3)) * 8));
        }
#pragma unroll
        for (int i = 0; i < 4; ++i)
#pragma unroll
            for (int j = 0; j < 4; ++j)
                acc[i][j] = __builtin_amdgcn_mfma_f32_16x16x32_bf16(
                    a_frag[i], b_frag[j], acc[i][j], 0, 0, 0);
        __syncthreads();
    }

    // C/D map: col = lane&15, row = (lane>>4)*4 + reg
    const int cr = quad * 4;
    const int cc = fr;
#pragma unroll
    for (int i = 0; i < 4; ++i) {
        int grow = m0 + wm + i * 16 + cr;
#pragma unroll
        for (int j = 0; j < 4; ++j) {
            int gcol = n0 + wn + j * 16 + cc;
            float bv = bias[gcol];
#pragma unroll
            for (int r = 0; r < 4; ++r)
                C[(size_t)(grow + r) * N + gcol] =
                    __float2bfloat16(acc[i][j][r] + bv);
        }
    }
}

// ---------------------------------------------------------------------------
// V transpose: vT[(b*H+h)*64+d][s] = qkv[(b*S+s)*3072 + 2048 + h*64 + d].
// ---------------------------------------------------------------------------
__global__ __launch_bounds__(256) void vtrans_kernel(
    const __hip_bfloat16* __restrict__ qkv, __hip_bfloat16* __restrict__ vT)
{
    __shared__ __hip_bfloat16 Ts[256 * 72];
    const int bh = blockIdx.x;
    const int b = bh >> 4, h = bh & 15;
    const int s0 = blockIdx.y * 256;
    const int tid = threadIdx.x;

    const __hip_bfloat16* g =
        qkv + (size_t)(b * SS + s0 + tid) * 3072 + 2048 + h * 64;
#pragma unroll
    for (int j = 0; j < 8; ++j)
        *(short8*)&Ts[tid * 72 + j * 8] = *(const short8*)(g + j * 8);
    __syncthreads();

    const int d  = tid >> 2;
    const int sb = (tid & 3) * 64;
    __hip_bfloat16* o = vT + (size_t)(bh * 64 + d) * SS + s0 + sb;
#pragma unroll
    for (int j = 0; j < 8; ++j) {
        short8 p;
#pragma unroll
        for (int i = 0; i < 8; ++i)
            p[i] = *(const short*)&Ts[(sb + j * 8 + i) * 72 + d];
        *(short8*)(o + j * 8) = p;
    }
}

// ---------------------------------------------------------------------------
// Proj GEMM: 64x128 tile (1024 blocks = 4/CU), BK=32, fp32 out + bias.
// Same XOR k-chunk swizzle as gemm_qkv.
// ---------------------------------------------------------------------------
__global__ __launch_bounds__(256) void gemm_proj(
    const __hip_bfloat16* __restrict__ A,   // M x K row-major
    const __hip_bfloat16* __restrict__ Bt,  // N x K row-major
    const float* __restrict__ bias,
    float* __restrict__ C,
    int M, int K, int N)
{
    __shared__ __hip_bfloat16 As[64 * 32];   // 4 KB
    __shared__ __hip_bfloat16 Bs[128 * 32];  // 8 KB

    const int tid  = threadIdx.x;
    const int wave = tid >> 6;
    const int lane = tid & 63;
    const int m0 = blockIdx.x * 64;
    const int n0 = blockIdx.y * 128;
    const int wm = (wave & 1) * 32;
    const int wn = (wave >> 1) * 64;

    float4v acc[2][4];
#pragma unroll
    for (int i = 0; i < 2; ++i)
#pragma unroll
        for (int j = 0; j < 4; ++j) acc[i][j] = (float4v){0.f, 0.f, 0.f, 0.f};

    const int fr = lane & 15;
    const int quad = lane >> 4;
    const short* AsS = (const short*)As;
    const short* BsS = (const short*)Bs;

    for (int k0 = 0; k0 < K; k0 += 32) {
        {   // A tile: 256 chunks, one per thread
            int c = tid;
            int kk = (((c & 3) ^ ((c >> 3) & 3)) * 8);
            const __hip_bfloat16* ga = A + (size_t)(m0 + (c >> 2)) * K + k0 + kk;
            char* la = (char*)As + (wave << 10);
            __builtin_amdgcn_global_load_lds(
                (const __attribute__((address_space(1))) void*)ga,
                (__attribute__((address_space(3))) void*)la, 16, 0, 0);
        }
#pragma unroll
        for (int j = 0; j < 2; ++j) {  // B tile: 512 chunks
            int c = j * 256 + tid;
            int kk = (((c & 3) ^ ((c >> 3) & 3)) * 8);
            const __hip_bfloat16* gb = Bt + (size_t)(n0 + (c >> 2)) * K + k0 + kk;
            char* lb = (char*)Bs + j * 4096 + (wave << 10);
            __builtin_amdgcn_global_load_lds(
                (const __attribute__((address_space(1))) void*)gb,
                (__attribute__((address_space(3))) void*)lb, 16, 0, 0);
        }
        __syncthreads();

        short8 a_frag[2], b_frag[4];
#pragma unroll
        for (int i = 0; i < 2; ++i) {
            int ra = wm + i * 16 + fr;
            a_frag[i] = *(const short8*)(AsS + ra * 32 + ((quad ^ ((ra >> 1) & 3)) * 8));
        }
#pragma unroll
        for (int j = 0; j < 4; ++j) {
            int rb = wn + j * 16 + fr;
            b_frag[j] = *(const short8*)(BsS + rb * 32 + ((quad ^ ((rb >> 1) & 3)) * 8));
        }
#pragma unroll
        for (int i = 0; i < 2; ++i)
#pragma unroll
            for (int j = 0; j < 4; ++j)
                acc[i][j] = __builtin_amdgcn_mfma_f32_16x16x32_bf16(
                    a_frag[i], b_frag[j], acc[i][j], 0, 0, 0);
        __syncthreads();
    }

    const int cr = quad * 4;
    const int cc = fr;
#pragma unroll
    for (int i = 0; i < 2; ++i) {
        int grow = m0 + wm + i * 16 + cr;
#pragma unroll
        for (int j = 0; j < 4; ++j) {
            int gcol = n0 + wn + j * 16 + cc;
            float bv = bias[gcol];
#pragma unroll
            for (int r = 0; r < 4; ++r)
                C[(size_t)(grow + r) * N + gcol] = acc[i][j][r] + bv;
        }
    }
}

// ---------------------------------------------------------------------------
// MFMA causal flash attention, no-max softmax (scores bounded; exp(-1e10)=0).
// Block: (b,h) x 128 queries, 4 waves x (2 x 16q subtiles). 64-key tiles.
// PSTR=72 shorts (144 B stride, odd multiple of 16 B) -> already 2-way banks.
// ---------------------------------------------------------------------------
#define PSTR 72

__global__ __launch_bounds__(256) void attn_mfma_kernel(
    const __hip_bfloat16* __restrict__ qkv,
    const __hip_bfloat16* __restrict__ vT,
    __hip_bfloat16* __restrict__ aout)
{
    const int bh = blockIdx.x;
    const int b = bh / HH, h = bh % HH;
    const int q0 = ((int)gridDim.y - 1 - (int)blockIdx.y) * 128;  // heavy first

    __shared__ __hip_bfloat16 Ks[64 * PSTR];     // [key][d]
    __shared__ __hip_bfloat16 Vs[64 * PSTR];     // V^T: [d][key]
    __shared__ __hip_bfloat16 Ps[4][32 * PSTR];  // per-wave P, [q_local][key]

    const int tid  = threadIdx.x;
    const int wave = tid >> 6;
    const int lane = tid & 63;
    const int quad = lane >> 4;
    const int l16  = lane & 15;

    short8 qf[2][2];
#pragma unroll
    for (int t = 0; t < 2; ++t) {
        const __hip_bfloat16* qp = qkv +
            (size_t)(b * SS + q0 + wave * 32 + t * 16 + l16) * 3072 + h * 64 + quad * 8;
        qf[t][0] = *(const short8*)qp;
        qf[t][1] = *(const short8*)(qp + 32);
    }

    float4v o_acc[2][4];
    float l_acc[2][4];
#pragma unroll
    for (int t = 0; t < 2; ++t)
#pragma unroll
        for (int nt = 0; nt < 4; ++nt) o_acc[t][nt] = (float4v){0.f, 0.f, 0.f, 0.f};
#pragma unroll
    for (int t = 0; t < 2; ++t)
#pragma unroll
        for (int r = 0; r < 4; ++r) l_acc[t][r] = 0.f;

    const int sk  = tid & 63;
    const int sdo = (tid >> 6) * 16;
    const int vd  = tid >> 2;
    const int vko = (tid & 3) * 16;
    const int qmin_w = q0 + wave * 32;
    const int nkt = q0 / 64 + 2;

    for (int kt = 0; kt < nkt; ++kt) {
        const int k0 = kt * 64;
        __syncthreads();
        {
            const __hip_bfloat16* kr =
                qkv + (size_t)(b * SS + k0 + sk) * 3072 + 1024 + h * 64 + sdo;
            *(short8*)&Ks[sk * PSTR + sdo]     = *(const short8*)kr;
            *(short8*)&Ks[sk * PSTR + sdo + 8] = *(const short8*)(kr + 8);
            const __hip_bfloat16* vr = vT + (size_t)(bh * 64 + vd) * SS + k0 + vko;
            *(short8*)&Vs[vd * PSTR + vko]     = *(const short8*)vr;
            *(short8*)&Vs[vd * PSTR + vko + 8] = *(const short8*)(vr + 8);
        }
        __syncthreads();
        if (k0 > qmin_w + 31) continue;

        const short* ks = (const short*)Ks;
        float4v sacc[2][4];
#pragma unroll
        for (int t = 0; t < 2; ++t)
#pragma unroll
            for (int nt = 0; nt < 4; ++nt) sacc[t][nt] = (float4v){0.f, 0.f, 0.f, 0.f};
#pragma unroll
        for (int kc = 0; kc < 2; ++kc)
#pragma unroll
            for (int nt = 0; nt < 4; ++nt) {
                short8 kb = *(const short8*)(ks + (nt * 16 + l16) * PSTR + kc * 32 + quad * 8);
                sacc[0][nt] = __builtin_amdgcn_mfma_f32_16x16x32_bf16(qf[0][kc], kb, sacc[0][nt], 0, 0, 0);
                sacc[1][nt] = __builtin_amdgcn_mfma_f32_16x16x32_bf16(qf[1][kc], kb, sacc[1][nt], 0, 0, 0);
            }

        const bool needmask = (k0 + 63 > qmin_w);
        __hip_bfloat16* pw = Ps[wave];
#pragma unroll
        for (int t = 0; t < 2; ++t)
#pragma unroll
            for (int nt = 0; nt < 4; ++nt) {
                int kk = k0 + nt * 16 + l16;
#pragma unroll
                for (int r = 0; r < 4; ++r) {
                    float s = sacc[t][nt][r];
                    if (needmask) {
                        int qq = qmin_w + t * 16 + quad * 4 + r;
                        if (kk > qq) s = -1e10f;
                    }
                    float p = __expf(s);
                    l_acc[t][r] += p;
                    pw[(t * 16 + quad * 4 + r) * PSTR + nt * 16 + l16] =
                        __float2bfloat16(p);
                }
            }

        const short* ps = (const short*)pw;
        const short* vs = (const short*)Vs;
#pragma unroll
        for (int kc = 0; kc < 2; ++kc) {
            short8 pa0 = *(const short8*)(ps + (0 * 16 + l16) * PSTR + kc * 32 + quad * 8);
            short8 pa1 = *(const short8*)(ps + (1 * 16 + l16) * PSTR + kc * 32 + quad * 8);
#pragma unroll
            for (int nt = 0; nt < 4; ++nt) {
                short8 vb = *(const short8*)(vs + (nt * 16 + l16) * PSTR + kc * 32 + quad * 8);
                o_acc[0][nt] = __builtin_amdgcn_mfma_f32_16x16x32_bf16(pa0, vb, o_acc[0][nt], 0, 0, 0);
                o_acc[1][nt] = __builtin_amdgcn_mfma_f32_16x16x32_bf16(pa1, vb, o_acc[1][nt], 0, 0, 0);
            }
        }
    }

#pragma unroll
    for (int t = 0; t < 2; ++t)
#pragma unroll
        for (int r = 0; r < 4; ++r) {
            float l = l_acc[t][r];
            l += __shfl_xor(l, 1);
            l += __shfl_xor(l, 2);
            l += __shfl_xor(l, 4);
            l += __shfl_xor(l, 8);
            float inv = 1.f / l;
            int row = q0 + wave * 32 + t * 16 + quad * 4 + r;
            __hip_bfloat16* op = aout + (size_t)(b * SS + row) * NXX + h * 64 + l16;
#pragma unroll
            for (int nt = 0; nt < 4; ++nt)
                op[nt * 16] = __float2bfloat16(o_acc[t][nt][r] * inv);
        }
}

// ---------------------------------------------------------------------------
// Workspace (~88 MB):
//   [0, 48M)    qkv bf16 (Q scaled 1/8, K, V rows)
//   [48, 64M)   vT bf16 [b,h,d,s]
//   [64, 80M)   xb bf16 -- reused as amid after QKV GEMM
//   [80, 86M)   wT_attn bf16 (Q rows pre-scaled)
//   [86, 88M)   wT_proj bf16
//   [88M, +12K) bias_s fp32
// ---------------------------------------------------------------------------
extern "C" void kernel_launch(void* const* d_in, const int* in_sizes, int n_in,
                              void* d_out, int out_size, void* d_ws, size_t ws_size,
                              hipStream_t stream)
{
    const float* x      = (const float*)d_in[0];
    const float* w_attn = (const float*)d_in[1];
    const float* b_attn = (const float*)d_in[2];
    const float* w_proj = (const float*)d_in[3];
    const float* b_proj = (const float*)d_in[4];
    float* out = (float*)d_out;

    char* ws = (char*)d_ws;
    __hip_bfloat16* qkv     = (__hip_bfloat16*)ws;
    __hip_bfloat16* vT      = (__hip_bfloat16*)(ws + (size_t)48 * 1024 * 1024);
    __hip_bfloat16* xb      = (__hip_bfloat16*)(ws + (size_t)64 * 1024 * 1024);
    __hip_bfloat16* amid    = xb;
    __hip_bfloat16* wT_attn = (__hip_bfloat16*)(ws + (size_t)80 * 1024 * 1024);
    __hip_bfloat16* wT_proj = (__hip_bfloat16*)(ws + (size_t)86 * 1024 * 1024);
    float*          bias_s  = (float*)(ws + (size_t)88 * 1024 * 1024);

    dim3 blk(256);

    prep_kernel<<<dim3(12289), blk, 0, stream>>>(
        x, xb, w_attn, wT_attn, w_proj, wT_proj, b_attn, bias_s);

    gemm_qkv<<<dim3(MM / 128, 24), blk, 0, stream>>>(
        xb, wT_attn, bias_s, qkv, MM, NXX, 3 * NXX);

    vtrans_kernel<<<dim3(BB * HH, SS / 256), blk, 0, stream>>>(qkv, vT);

    attn_mfma_kernel<<<dim3(BB * HH, SS / 128), blk, 0, stream>>>(qkv, vT, amid);

    gemm_proj<<<dim3(MM / 64, NXX / 128), blk, 0, stream>>>(
        amid, wT_proj, b_proj, out, MM, NXX, NXX);
}